// Round 5
// baseline (884.813 us; speedup 1.0000x reference)
//
#include <hip/hip_runtime.h>
#include <stdint.h>

#define NROWS 8192
#define KCODES 8192
#define DIM 512
#define BETA 0.25f

// fallback fp32 path tiling
#define BM 128
#define BN 128
#define BD 16
#define KCHUNK 512

// fast path
#define MARGIN_T 1.0e-4f
#define MAXCAND 24

typedef unsigned long long u64;
typedef __attribute__((ext_vector_type(8))) short bf16x8;
typedef __attribute__((ext_vector_type(4))) float f32x4;
typedef __attribute__((ext_vector_type(4))) unsigned short us4;

// ---------------- shared helpers ----------------

__device__ inline unsigned short f2bf_rne(float x) {
    union { float f; unsigned u; } v; v.f = x;
    unsigned r = v.u + 0x7FFFu + ((v.u >> 16) & 1u);
    return (unsigned short)(r >> 16);
}
__device__ inline float bf2f(unsigned short h) {
    union { unsigned u; float f; } v; v.u = ((unsigned)h) << 16;
    return v.f;
}
__device__ inline bool lexlt(float av, int ai, float bv, int bi) {
    return (av < bv) || (av == bv && ai < bi);
}
__device__ inline void ins2(float& v1, int& i1, float& v2, int& i2, float nv, int ni) {
    if (lexlt(nv, ni, v1, i1)) { v2 = v1; i2 = i1; v1 = nv; i1 = ni; }
    else if (lexlt(nv, ni, v2, i2)) { v2 = nv; i2 = ni; }
}
__device__ inline void gload_lds16(const void* g, void* l) {
    __builtin_amdgcn_global_load_lds(
        (const __attribute__((address_space(1))) void*)g,
        (__attribute__((address_space(3))) void*)l, 16, 0, 0);
}

// ---------------- common: numpy-exact row norm ----------------
__global__ __launch_bounds__(256) void rownorm_kernel(const float* __restrict__ lat,
                                                      float* __restrict__ Srow) {
    __shared__ float buf[4][DIM];
    const int w = threadIdx.x >> 6;
    const int lane = threadIdx.x & 63;
    const int n = blockIdx.x * 4 + w;
    {
        const float4* p = (const float4*)(lat + (size_t)n * DIM);
        float4 v0 = p[lane * 2];
        float4 v1 = p[lane * 2 + 1];
        float4* q = (float4*)buf[w];
        q[lane * 2] = v0;
        q[lane * 2 + 1] = v1;
    }
    __syncthreads();
    if (lane < 32) {
        const int m = lane >> 3;
        const int j = lane & 7;
        const float* b = buf[w] + 128 * m + j;
        float r = b[0] * b[0];
        #pragma unroll
        for (int t = 1; t < 16; ++t) { float x = b[8 * t]; r += x * x; }
        float s1 = r + __shfl_down(r, 1);
        float s2 = s1 + __shfl_down(s1, 2);
        float s3 = s2 + __shfl_down(s2, 4);
        float x0 = s3 + __shfl_down(s3, 8);
        float S = x0 + __shfl_down(x0, 16);
        if (lane == 0) Srow[n] = S;
    }
}

// ================= FAST PATH =================

__global__ __launch_bounds__(256) void convert_kernel(
        const float* __restrict__ lat, const float* __restrict__ cb,
        unsigned short* __restrict__ Ahi, unsigned short* __restrict__ Alo,
        unsigned short* __restrict__ Bhi, unsigned short* __restrict__ Blo,
        float* __restrict__ loss_accum) {
    size_t i = (size_t)blockIdx.x * 256 + threadIdx.x;
    if (i == 0) *loss_accum = 0.0f;
    const size_t half = (size_t)NROWS * DIM / 4;
    const float* src; unsigned short *hi, *lo;
    if (i < half) { src = lat; hi = Ahi; lo = Alo; }
    else { src = cb; hi = Bhi; lo = Blo; i -= half; }
    float4 v = ((const float4*)src)[i];
    us4 h, l;
    h.x = f2bf_rne(v.x); l.x = f2bf_rne(v.x - bf2f(h.x));
    h.y = f2bf_rne(v.y); l.y = f2bf_rne(v.y - bf2f(h.y));
    h.z = f2bf_rne(v.z); l.z = f2bf_rne(v.z - bf2f(h.z));
    h.w = f2bf_rne(v.w); l.w = f2bf_rne(v.w - bf2f(h.w));
    *(us4*)&hi[i * 4] = h;
    *(us4*)&lo[i * 4] = l;
}

// 256x256 tile, BK=64, 8 waves (2x4), double-buffered LDS with prefetch-before-
// compute (T3-minimum). Virtual K = 1536: segments (Ahi,Bhi),(Alo,Bhi),(Ahi,Blo)
// give acc = ah.bh + al.bh + ah.bl. Per-wave 128x64 output; top-2 per row per
// wave (lex (t,idx)); t = -2*acc (row-constant S dropped, ranking only).
__global__ __launch_bounds__(512) void mfma_dist_kernel(
        const unsigned short* __restrict__ Ahi, const unsigned short* __restrict__ Alo,
        const unsigned short* __restrict__ Bhi, const unsigned short* __restrict__ Blo,
        float4* __restrict__ top2) {
    __shared__ unsigned short sA[2][256][64];   // 64 KiB
    __shared__ unsigned short sB[2][256][64];   // 64 KiB
    // XCD-aware bijective swizzle (1024 blocks, 1024 % 8 == 0)
    int bid = blockIdx.x;
    int swz = (bid & 7) * 128 + (bid >> 3);
    const int bx = swz & 31;
    const int by = swz >> 5;
    const int row0 = bx * 256, col0 = by * 256;
    const int tid = threadIdx.x;
    const int w = tid >> 6, l = tid & 63;
    const int wm = w >> 2, wn = w & 3;          // 2 x 4 wave grid
    const int g = l >> 4, c = l & 15;

    f32x4 acc[8][4];
    #pragma unroll
    for (int a = 0; a < 8; ++a)
        #pragma unroll
        for (int b = 0; b < 4; ++b)
            acc[a][b] = (f32x4){0.f, 0.f, 0.f, 0.f};

    const int lr = l >> 3;          // lane row within 8-row stripe
    const int lc = l & 7;           // lane col-chunk

    auto stage = [&](int bsel, int kt) {
        const int sg = kt >> 3;                 // segment 0,1,2
        const int d0 = (kt & 7) * 64;
        const unsigned short* Asrc = (sg == 1) ? Alo : Ahi;
        const unsigned short* Bsrc = (sg == 2) ? Blo : Bhi;
        #pragma unroll
        for (int i = 0; i < 4; ++i) {
            const int r0 = w * 32 + i * 8;      // wave-uniform row block
            const int r = r0 + lr;
            const int chunk = lc ^ (r & 7);     // pre-swizzled global source
            gload_lds16(Asrc + (size_t)(row0 + r) * DIM + d0 + chunk * 8,
                        &sA[bsel][r0][0]);
            gload_lds16(Bsrc + (size_t)(col0 + r) * DIM + d0 + chunk * 8,
                        &sB[bsel][r0][0]);
        }
    };

    auto compute = [&](int bsel) {
        #pragma unroll
        for (int kk = 0; kk < 2; ++kk) {
            const int colbase = kk * 32 + g * 8;
            bf16x8 af[8], bfr[4];
            #pragma unroll
            for (int f = 0; f < 8; ++f) {
                int ra = wm * 128 + f * 16 + c;
                int ca = colbase ^ ((ra & 7) << 3);   // swizzled read
                af[f] = *(const bf16x8*)&sA[bsel][ra][ca];
            }
            #pragma unroll
            for (int f = 0; f < 4; ++f) {
                int rb = wn * 64 + f * 16 + c;
                int cb2 = colbase ^ ((rb & 7) << 3);
                bfr[f] = *(const bf16x8*)&sB[bsel][rb][cb2];
            }
            #pragma unroll
            for (int fm = 0; fm < 8; ++fm)
                #pragma unroll
                for (int fn = 0; fn < 4; ++fn)
                    acc[fm][fn] = __builtin_amdgcn_mfma_f32_16x16x32_bf16(
                        af[fm], bfr[fn], acc[fm][fn], 0, 0, 0);
        }
    };

    stage(0, 0);
    __syncthreads();                 // drains vmcnt(0): buf0 ready
    int cur = 0;
    for (int kt = 0; kt < 24; ++kt) {
        if (kt < 23) stage(cur ^ 1, kt + 1);   // issue BEFORE compute: overlap
        compute(cur);
        __syncthreads();             // one drain+barrier per K-step
        cur ^= 1;
    }

    // epilogue: per-row top-2 over this wave's 64 codes
    #pragma unroll
    for (int fm = 0; fm < 8; ++fm) {
        #pragma unroll
        for (int r = 0; r < 4; ++r) {
            float v1 = -2.0f * acc[fm][0][r];
            int i1 = col0 + wn * 64 + c;
            float v2 = 3.4e38f; int i2 = 0x7FFFFFFF;
            #pragma unroll
            for (int fn = 1; fn < 4; ++fn) {
                float nv = -2.0f * acc[fm][fn][r];
                int ni = col0 + wn * 64 + fn * 16 + c;
                ins2(v1, i1, v2, i2, nv, ni);
            }
            #pragma unroll
            for (int mask = 1; mask <= 8; mask <<= 1) {
                float o1 = __shfl_xor(v1, mask); int oi1 = __shfl_xor(i1, mask);
                float o2 = __shfl_xor(v2, mask); int oi2 = __shfl_xor(i2, mask);
                ins2(v1, i1, v2, i2, o1, oi1);
                ins2(v1, i1, v2, i2, o2, oi2);
            }
            if (c == 0) {
                int row = row0 + wm * 128 + fm * 16 + g * 4 + r;
                float4 e;
                e.x = v1; e.y = __int_as_float(i1);
                e.z = v2; e.w = __int_as_float(i2);
                top2[(size_t)row * 128 + by * 4 + wn] = e;
            }
        }
    }
}

// per row: global approx min over 256 stored entries, margin candidates,
// exact numpy-fp32-chain rescore, lexicographic winner.
__global__ __launch_bounds__(256) void select_rescore_kernel(
        const float* __restrict__ lat, const float* __restrict__ cb,
        const float* __restrict__ Srow, const float4* __restrict__ top2,
        int* __restrict__ idxfinal) {
    __shared__ float fr[DIM];
    __shared__ float svals[128];
    __shared__ int sidx[128];
    __shared__ int scnt;
    __shared__ int scand[MAXCAND];
    __shared__ float cs[MAXCAND];
    __shared__ int ck[MAXCAND];
    const int n = blockIdx.x;
    const int t = threadIdx.x;

    fr[t] = lat[(size_t)n * DIM + t];
    fr[t + 256] = lat[(size_t)n * DIM + t + 256];
    if (t == 0) scnt = 0;

    float4 e;
    float pv = 3.4e38f; int pi = 0x7FFFFFFF;
    if (t < 128) {
        e = top2[(size_t)n * 128 + t];
        int e1 = __float_as_int(e.y), e2 = __float_as_int(e.w);
        pv = e.x; pi = e1;
        if (lexlt(e.z, e2, pv, pi)) { pv = e.z; pi = e2; }
        svals[t] = pv; sidx[t] = pi;
    }
    __syncthreads();
    for (int s = 64; s > 0; s >>= 1) {
        if (t < s && lexlt(svals[t + s], sidx[t + s], svals[t], sidx[t])) {
            svals[t] = svals[t + s]; sidx[t] = sidx[t + s];
        }
        __syncthreads();
    }
    const float gthr = svals[0] + MARGIN_T;
    __syncthreads();
    if (t < 128) {
        if (e.x <= gthr) {
            int p = atomicAdd(&scnt, 1);
            if (p < MAXCAND) scand[p] = __float_as_int(e.y);
        }
        if (e.z <= gthr) {
            int p = atomicAdd(&scnt, 1);
            if (p < MAXCAND) scand[p] = __float_as_int(e.w);
        }
    }
    __syncthreads();
    int m = scnt < MAXCAND ? scnt : MAXCAND;
    if (t < m) {
        int k = scand[t];
        const float* crow = cb + (size_t)k * DIM;
        float acc = 0.0f;
        for (int d = 0; d < DIM; d += 4) {   // exact ascending-d FMA chain
            float4 b = *(const float4*)(crow + d);
            acc = __builtin_fmaf(fr[d + 0], b.x, acc);
            acc = __builtin_fmaf(fr[d + 1], b.y, acc);
            acc = __builtin_fmaf(fr[d + 2], b.z, acc);
            acc = __builtin_fmaf(fr[d + 3], b.w, acc);
        }
        cs[t] = __builtin_fmaf(-2.0f, acc, Srow[n]);
        ck[t] = k;
    }
    __syncthreads();
    if (t == 0) {
        float bv = cs[0]; int bi = ck[0];
        for (int q = 1; q < m; ++q)
            if (lexlt(cs[q], ck[q], bv, bi)) { bv = cs[q]; bi = ck[q]; }
        idxfinal[n] = bi;
    }
}

__global__ void finalize_idx_kernel(const float* __restrict__ lat,
                                    const float* __restrict__ cb,
                                    const int* __restrict__ idxfinal,
                                    float* __restrict__ out_q,
                                    float* __restrict__ out_idx,
                                    float* __restrict__ loss_accum) {
    int n = blockIdx.x;
    int t = threadIdx.x;
    int idx = idxfinal[n];
    const float2 q = ((const float2*)(cb + (size_t)idx * DIM))[t];
    const float2 l = ((const float2*)(lat + (size_t)n * DIM))[t];
    ((float2*)(out_q + (size_t)n * DIM))[t] = q;
    float dx = l.x - q.x, dy = l.y - q.y;
    float local = dx * dx + dy * dy;
    #pragma unroll
    for (int off = 32; off > 0; off >>= 1) local += __shfl_down(local, off);
    __shared__ float wsum[4];
    if ((t & 63) == 0) wsum[t >> 6] = local;
    __syncthreads();
    if (t == 0) {
        atomicAdd(loss_accum, wsum[0] + wsum[1] + wsum[2] + wsum[3]);
        out_idx[n] = (float)idx;
    }
}

// ================= FALLBACK (round-3 verified) =================

__global__ void init_ws_kernel(u64* __restrict__ best, float* __restrict__ loss_accum) {
    int i = blockIdx.x * blockDim.x + threadIdx.x;
    if (i < NROWS) best[i] = 0xFFFFFFFFFFFFFFFFULL;
    if (i == 0) *loss_accum = 0.0f;
}

__global__ __launch_bounds__(256) void dist_argmin_kernel(
        const float* __restrict__ lat, const float* __restrict__ cb,
        const float* __restrict__ Srow, u64* __restrict__ best) {
    __shared__ float As[BD][BM];
    __shared__ float Bs[BD][BN];
    const int tid = threadIdx.x;
    const int tx = tid & 15;
    const int ty = tid >> 4;
    const int row0 = blockIdx.x * BM;
    const int kbase = blockIdx.y * KCHUNK;

    int rowid[8];
    float Sr[8];
    #pragma unroll
    for (int i = 0; i < 8; ++i) {
        rowid[i] = row0 + ((i < 4) ? (ty * 4 + i) : (64 + ty * 4 + (i - 4)));
        Sr[i] = Srow[rowid[i]];
    }
    float bval[8];
    int bidx[8];
    #pragma unroll
    for (int i = 0; i < 8; ++i) { bval[i] = 3.4e38f; bidx[i] = 0; }

    for (int kt = 0; kt < KCHUNK; kt += BN) {
        float acc[8][8];
        #pragma unroll
        for (int i = 0; i < 8; ++i)
            #pragma unroll
            for (int j = 0; j < 8; ++j) acc[i][j] = 0.0f;
        for (int d0 = 0; d0 < DIM; d0 += BD) {
            __syncthreads();
            #pragma unroll
            for (int u = 0; u < 2; ++u) {
                int f = tid * 2 + u;
                int r = f >> 2;
                int dq = (f & 3) * 4;
                float4 va = *(const float4*)(lat + (size_t)(row0 + r) * DIM + d0 + dq);
                As[dq + 0][r] = va.x; As[dq + 1][r] = va.y;
                As[dq + 2][r] = va.z; As[dq + 3][r] = va.w;
                float4 vb = *(const float4*)(cb + (size_t)(kbase + kt + r) * DIM + d0 + dq);
                Bs[dq + 0][r] = vb.x; Bs[dq + 1][r] = vb.y;
                Bs[dq + 2][r] = vb.z; Bs[dq + 3][r] = vb.w;
            }
            __syncthreads();
            #pragma unroll
            for (int dd = 0; dd < BD; ++dd) {
                float4 a0 = *(const float4*)&As[dd][ty * 4];
                float4 a1 = *(const float4*)&As[dd][64 + ty * 4];
                float4 b0 = *(const float4*)&Bs[dd][tx * 4];
                float4 b1 = *(const float4*)&Bs[dd][64 + tx * 4];
                float av[8] = {a0.x, a0.y, a0.z, a0.w, a1.x, a1.y, a1.z, a1.w};
                float bv[8] = {b0.x, b0.y, b0.z, b0.w, b1.x, b1.y, b1.z, b1.w};
                #pragma unroll
                for (int i = 0; i < 8; ++i)
                    #pragma unroll
                    for (int j = 0; j < 8; ++j)
                        acc[i][j] = __builtin_fmaf(av[i], bv[j], acc[i][j]);
            }
        }
        #pragma unroll
        for (int j = 0; j < 8; ++j) {
            int cj = (j < 4) ? (tx * 4 + j) : (64 + tx * 4 + (j - 4));
            int k = kbase + kt + cj;
            #pragma unroll
            for (int i = 0; i < 8; ++i) {
                float s = __builtin_fmaf(-2.0f, acc[i][j], Sr[i]);
                if (s < bval[i]) { bval[i] = s; bidx[i] = k; }
            }
        }
    }
    #pragma unroll
    for (int i = 0; i < 8; ++i) {
        float v = bval[i];
        int ix = bidx[i];
        #pragma unroll
        for (int off = 8; off > 0; off >>= 1) {
            float ov = __shfl_xor(v, off, 16);
            int oi = __shfl_xor(ix, off, 16);
            if (ov < v || (ov == v && oi < ix)) { v = ov; ix = oi; }
        }
        if (tx == 0) {
            unsigned u = __float_as_uint(v);
            unsigned key = (u & 0x80000000u) ? ~u : (u | 0x80000000u);
            u64 pk = ((u64)key << 32) | (unsigned)ix;
            atomicMin(&best[rowid[i]], pk);
        }
    }
}

__global__ void finalize_kernel(const float* __restrict__ lat,
                                const float* __restrict__ cb,
                                const u64* __restrict__ best,
                                float* __restrict__ out_q,
                                float* __restrict__ out_idx,
                                float* __restrict__ loss_accum) {
    int n = blockIdx.x;
    int t = threadIdx.x;
    int idx = (int)(best[n] & 0xFFFFFFFFULL);
    const float2 q = ((const float2*)(cb + (size_t)idx * DIM))[t];
    const float2 l = ((const float2*)(lat + (size_t)n * DIM))[t];
    ((float2*)(out_q + (size_t)n * DIM))[t] = q;
    float dx = l.x - q.x, dy = l.y - q.y;
    float local = dx * dx + dy * dy;
    #pragma unroll
    for (int off = 32; off > 0; off >>= 1) local += __shfl_down(local, off);
    __shared__ float wsum[4];
    if ((t & 63) == 0) wsum[t >> 6] = local;
    __syncthreads();
    if (t == 0) {
        atomicAdd(loss_accum, wsum[0] + wsum[1] + wsum[2] + wsum[3]);
        out_idx[n] = (float)idx;
    }
}

__global__ void write_loss_kernel(const float* __restrict__ loss_accum,
                                  float* __restrict__ out_loss) {
    *out_loss = (1.0f + BETA) * (*loss_accum) * (1.0f / (float)((size_t)NROWS * DIM));
}

// ---------------- launch ----------------

extern "C" void kernel_launch(void* const* d_in, const int* in_sizes, int n_in,
                              void* d_out, int out_size, void* d_ws, size_t ws_size,
                              hipStream_t stream) {
    const float* lat = (const float*)d_in[0];   // [8,1024,512] f32
    const float* cb  = (const float*)d_in[1];   // [8192,512] f32

    float* out = (float*)d_out;
    float* out_q    = out;
    float* out_loss = out + (size_t)NROWS * DIM;
    float* out_idx  = out_loss + 1;

    char* ws = (char*)d_ws;

    // fast-path layout (identical to round 4 — proven to fit)
    const size_t MATB = (size_t)NROWS * DIM * 2;            // 8 MiB per bf16 matrix
    unsigned short* Ahi = (unsigned short*)(ws);
    unsigned short* Alo = (unsigned short*)(ws + MATB);
    unsigned short* Bhi = (unsigned short*)(ws + 2 * MATB);
    unsigned short* Blo = (unsigned short*)(ws + 3 * MATB);
    float4* top2        = (float4*)(ws + 4 * MATB);         // 16 MiB
    char* tail          = ws + 4 * MATB + (size_t)NROWS * 128 * 16;
    float* SrowF        = (float*)tail;                     // 32 KiB
    int*   idxfinal     = (int*)(tail + 32768);             // 32 KiB
    float* lossF        = (float*)(tail + 65536);           // 4 B
    const size_t REQ    = (size_t)(tail - ws) + 65536 + 64;

    if (ws_size >= REQ) {
        hipLaunchKernelGGL(convert_kernel, dim3(2 * NROWS * DIM / 4 / 256), dim3(256), 0, stream,
                           lat, cb, Ahi, Alo, Bhi, Blo, lossF);
        hipLaunchKernelGGL(rownorm_kernel, dim3(NROWS / 4), dim3(256), 0, stream, lat, SrowF);
        hipLaunchKernelGGL(mfma_dist_kernel, dim3((NROWS / 256) * (KCODES / 256)), dim3(512),
                           0, stream, Ahi, Alo, Bhi, Blo, top2);
        hipLaunchKernelGGL(select_rescore_kernel, dim3(NROWS), dim3(256), 0, stream,
                           lat, cb, SrowF, top2, idxfinal);
        hipLaunchKernelGGL(finalize_idx_kernel, dim3(NROWS), dim3(256), 0, stream,
                           lat, cb, idxfinal, out_q, out_idx, lossF);
        hipLaunchKernelGGL(write_loss_kernel, dim3(1), dim3(1), 0, stream, lossF, out_loss);
    } else {
        // round-3 verified fallback
        u64*   best       = (u64*)(ws + 0);
        float* Srow       = (float*)(ws + 65536);
        float* loss_accum = (float*)(ws + 98304);
        hipLaunchKernelGGL(init_ws_kernel, dim3(32), dim3(256), 0, stream, best, loss_accum);
        hipLaunchKernelGGL(rownorm_kernel, dim3(NROWS / 4), dim3(256), 0, stream, lat, Srow);
        hipLaunchKernelGGL(dist_argmin_kernel, dim3(NROWS / BM, KCODES / KCHUNK), dim3(256),
                           0, stream, lat, cb, Srow, best);
        hipLaunchKernelGGL(finalize_kernel, dim3(NROWS), dim3(256), 0, stream,
                           lat, cb, best, out_q, out_idx, loss_accum);
        hipLaunchKernelGGL(write_loss_kernel, dim3(1), dim3(1), 0, stream, loss_accum, out_loss);
    }
}

// Round 6
// 880.992 us; speedup vs baseline: 1.0043x; 1.0043x over previous
//
#include <hip/hip_runtime.h>
#include <stdint.h>

#define NROWS 8192
#define KCODES 8192
#define DIM 512
#define BETA 0.25f

// fallback fp32 path tiling
#define BM 128
#define BN 128
#define BD 16
#define KCHUNK 512

// fast path
#define MARGIN_T 1.0e-4f
#define MAXCAND 24

typedef unsigned long long u64;
typedef __attribute__((ext_vector_type(8))) short bf16x8;
typedef __attribute__((ext_vector_type(4))) float f32x4;
typedef __attribute__((ext_vector_type(4))) unsigned short us4;

// ---------------- shared helpers ----------------

__device__ inline unsigned short f2bf_rne(float x) {
    union { float f; unsigned u; } v; v.f = x;
    unsigned r = v.u + 0x7FFFu + ((v.u >> 16) & 1u);
    return (unsigned short)(r >> 16);
}
__device__ inline float bf2f(unsigned short h) {
    union { unsigned u; float f; } v; v.u = ((unsigned)h) << 16;
    return v.f;
}
__device__ inline bool lexlt(float av, int ai, float bv, int bi) {
    return (av < bv) || (av == bv && ai < bi);
}
__device__ inline void ins2(float& v1, int& i1, float& v2, int& i2, float nv, int ni) {
    if (lexlt(nv, ni, v1, i1)) { v2 = v1; i2 = i1; v1 = nv; i1 = ni; }
    else if (lexlt(nv, ni, v2, i2)) { v2 = nv; i2 = ni; }
}
__device__ inline void gload_lds16(const void* g, void* l) {
    __builtin_amdgcn_global_load_lds(
        (const __attribute__((address_space(1))) void*)g,
        (__attribute__((address_space(3))) void*)l, 16, 0, 0);
}

// ---------------- common: numpy-exact row norm ----------------
__global__ __launch_bounds__(256) void rownorm_kernel(const float* __restrict__ lat,
                                                      float* __restrict__ Srow) {
    __shared__ float buf[4][DIM];
    const int w = threadIdx.x >> 6;
    const int lane = threadIdx.x & 63;
    const int n = blockIdx.x * 4 + w;
    {
        const float4* p = (const float4*)(lat + (size_t)n * DIM);
        float4 v0 = p[lane * 2];
        float4 v1 = p[lane * 2 + 1];
        float4* q = (float4*)buf[w];
        q[lane * 2] = v0;
        q[lane * 2 + 1] = v1;
    }
    __syncthreads();
    if (lane < 32) {
        const int m = lane >> 3;
        const int j = lane & 7;
        const float* b = buf[w] + 128 * m + j;
        float r = b[0] * b[0];
        #pragma unroll
        for (int t = 1; t < 16; ++t) { float x = b[8 * t]; r += x * x; }
        float s1 = r + __shfl_down(r, 1);
        float s2 = s1 + __shfl_down(s1, 2);
        float s3 = s2 + __shfl_down(s2, 4);
        float x0 = s3 + __shfl_down(s3, 8);
        float S = x0 + __shfl_down(x0, 16);
        if (lane == 0) Srow[n] = S;
    }
}

// ================= FAST PATH =================

__global__ __launch_bounds__(256) void convert_kernel(
        const float* __restrict__ lat, const float* __restrict__ cb,
        unsigned short* __restrict__ Ahi, unsigned short* __restrict__ Alo,
        unsigned short* __restrict__ Bhi, unsigned short* __restrict__ Blo,
        float* __restrict__ loss_accum) {
    size_t i = (size_t)blockIdx.x * 256 + threadIdx.x;
    if (i == 0) *loss_accum = 0.0f;
    const size_t half = (size_t)NROWS * DIM / 4;
    const float* src; unsigned short *hi, *lo;
    if (i < half) { src = lat; hi = Ahi; lo = Alo; }
    else { src = cb; hi = Bhi; lo = Blo; i -= half; }
    float4 v = ((const float4*)src)[i];
    us4 h, l;
    h.x = f2bf_rne(v.x); l.x = f2bf_rne(v.x - bf2f(h.x));
    h.y = f2bf_rne(v.y); l.y = f2bf_rne(v.y - bf2f(h.y));
    h.z = f2bf_rne(v.z); l.z = f2bf_rne(v.z - bf2f(h.z));
    h.w = f2bf_rne(v.w); l.w = f2bf_rne(v.w - bf2f(h.w));
    *(us4*)&hi[i * 4] = h;
    *(us4*)&lo[i * 4] = l;
}

// 256x256 tile, BK=64, 8 waves (2x4), double-buffered LDS, counted-vmcnt
// pipeline (raw barriers; vmcnt(8) mid-loop, never 0). Virtual K = 1536:
// segments (Ahi,Bhi),(Alo,Bhi),(Ahi,Blo) => acc = ah.bh + al.bh + ah.bl.
// Supertiled XCD mapping: XCD=bid&7 owns 4 by-panels (B stays L2-resident);
// bx swept in groups of 4 (A working set 2MB+B 2MB = L2-sized).
__global__ __launch_bounds__(512) void mfma_dist_kernel(
        const unsigned short* __restrict__ Ahi, const unsigned short* __restrict__ Alo,
        const unsigned short* __restrict__ Bhi, const unsigned short* __restrict__ Blo,
        float4* __restrict__ top2) {
    __shared__ unsigned short sA[2][256][64];   // 64 KiB
    __shared__ unsigned short sB[2][256][64];   // 64 KiB
    // supertiled XCD-aware mapping (bijective: 1024 blocks -> 32x32 tiles)
    const int bid = blockIdx.x;
    const int xcd = bid & 7;
    const int j = bid >> 3;            // 0..127 within XCD
    const int st = j >> 4;             // supertile (bx-group) 0..7
    const int tt = j & 15;
    const int bx = st * 4 + (tt & 3);  // 0..31
    const int by = xcd * 4 + (tt >> 2);// 0..31
    const int row0 = bx * 256, col0 = by * 256;
    const int tid = threadIdx.x;
    const int w = tid >> 6, l = tid & 63;
    const int wm = w >> 2, wn = w & 3;          // 2 x 4 wave grid
    const int g = l >> 4, c = l & 15;

    f32x4 acc[8][4];
    #pragma unroll
    for (int a = 0; a < 8; ++a)
        #pragma unroll
        for (int b = 0; b < 4; ++b)
            acc[a][b] = (f32x4){0.f, 0.f, 0.f, 0.f};

    const int lr = l >> 3;          // lane row within 8-row stripe
    const int lc = l & 7;           // lane col-chunk

    auto stage = [&](int bsel, int kt) {
        const int sg = kt >> 3;                 // segment 0,1,2
        const int d0 = (kt & 7) * 64;
        const unsigned short* Asrc = (sg == 1) ? Alo : Ahi;
        const unsigned short* Bsrc = (sg == 2) ? Blo : Bhi;
        #pragma unroll
        for (int i = 0; i < 4; ++i) {
            const int r0 = w * 32 + i * 8;      // wave-uniform row block
            const int r = r0 + lr;
            const int chunk = lc ^ (r & 7);     // pre-swizzled global source
            gload_lds16(Asrc + (size_t)(row0 + r) * DIM + d0 + chunk * 8,
                        &sA[bsel][r0][0]);
            gload_lds16(Bsrc + (size_t)(col0 + r) * DIM + d0 + chunk * 8,
                        &sB[bsel][r0][0]);
        }
    };

    auto compute = [&](int bsel) {
        #pragma unroll
        for (int kk = 0; kk < 2; ++kk) {
            const int colbase = kk * 32 + g * 8;
            bf16x8 af[8], bfr[4];
            #pragma unroll
            for (int f = 0; f < 8; ++f) {
                int ra = wm * 128 + f * 16 + c;
                int ca = colbase ^ ((ra & 7) << 3);   // swizzled read
                af[f] = *(const bf16x8*)&sA[bsel][ra][ca];
            }
            #pragma unroll
            for (int f = 0; f < 4; ++f) {
                int rb = wn * 64 + f * 16 + c;
                int cb2 = colbase ^ ((rb & 7) << 3);
                bfr[f] = *(const bf16x8*)&sB[bsel][rb][cb2];
            }
            #pragma unroll
            for (int fm = 0; fm < 8; ++fm)
                #pragma unroll
                for (int fn = 0; fn < 4; ++fn)
                    acc[fm][fn] = __builtin_amdgcn_mfma_f32_16x16x32_bf16(
                        af[fm], bfr[fn], acc[fm][fn], 0, 0, 0);
        }
    };

    stage(0, 0);                     // 8 loads in flight
    int cur = 0;
    for (int kt = 0; kt < 24; ++kt) {
        if (kt < 23) {
            stage(cur ^ 1, kt + 1);  // +8 -> 16 in flight
            // wait until <=8 outstanding: buf[cur]'s 8 have landed; next-tile
            // loads REMAIN in flight across the barrier (T4 counted vmcnt)
            asm volatile("s_waitcnt vmcnt(8)" ::: "memory");
        } else {
            asm volatile("s_waitcnt vmcnt(0)" ::: "memory");
        }
        __builtin_amdgcn_s_barrier();            // all waves' cur data ready
        asm volatile("" ::: "memory");
        __builtin_amdgcn_s_setprio(1);
        compute(cur);
        __builtin_amdgcn_s_setprio(0);
        asm volatile("" ::: "memory");
        __builtin_amdgcn_s_barrier();            // cur fully read; safe to overwrite
        asm volatile("" ::: "memory");
        cur ^= 1;
    }

    // epilogue: per-row top-2 over this wave's 64 codes (lex (t,idx)); t=-2*acc
    #pragma unroll
    for (int fm = 0; fm < 8; ++fm) {
        #pragma unroll
        for (int r = 0; r < 4; ++r) {
            float v1 = -2.0f * acc[fm][0][r];
            int i1 = col0 + wn * 64 + c;
            float v2 = 3.4e38f; int i2 = 0x7FFFFFFF;
            #pragma unroll
            for (int fn = 1; fn < 4; ++fn) {
                float nv = -2.0f * acc[fm][fn][r];
                int ni = col0 + wn * 64 + fn * 16 + c;
                ins2(v1, i1, v2, i2, nv, ni);
            }
            #pragma unroll
            for (int mask = 1; mask <= 8; mask <<= 1) {
                float o1 = __shfl_xor(v1, mask); int oi1 = __shfl_xor(i1, mask);
                float o2 = __shfl_xor(v2, mask); int oi2 = __shfl_xor(i2, mask);
                ins2(v1, i1, v2, i2, o1, oi1);
                ins2(v1, i1, v2, i2, o2, oi2);
            }
            if (c == 0) {
                int row = row0 + wm * 128 + fm * 16 + g * 4 + r;
                float4 e;
                e.x = v1; e.y = __int_as_float(i1);
                e.z = v2; e.w = __int_as_float(i2);
                top2[(size_t)row * 128 + by * 4 + wn] = e;
            }
        }
    }
}

// per row: global approx min over 256 stored entries, margin candidates,
// exact numpy-fp32-chain rescore, lexicographic winner.
__global__ __launch_bounds__(256) void select_rescore_kernel(
        const float* __restrict__ lat, const float* __restrict__ cb,
        const float* __restrict__ Srow, const float4* __restrict__ top2,
        int* __restrict__ idxfinal) {
    __shared__ float fr[DIM];
    __shared__ float svals[128];
    __shared__ int sidx[128];
    __shared__ int scnt;
    __shared__ int scand[MAXCAND];
    __shared__ float cs[MAXCAND];
    __shared__ int ck[MAXCAND];
    const int n = blockIdx.x;
    const int t = threadIdx.x;

    fr[t] = lat[(size_t)n * DIM + t];
    fr[t + 256] = lat[(size_t)n * DIM + t + 256];
    if (t == 0) scnt = 0;

    float4 e;
    float pv = 3.4e38f; int pi = 0x7FFFFFFF;
    if (t < 128) {
        e = top2[(size_t)n * 128 + t];
        int e1 = __float_as_int(e.y), e2 = __float_as_int(e.w);
        pv = e.x; pi = e1;
        if (lexlt(e.z, e2, pv, pi)) { pv = e.z; pi = e2; }
        svals[t] = pv; sidx[t] = pi;
    }
    __syncthreads();
    for (int s = 64; s > 0; s >>= 1) {
        if (t < s && lexlt(svals[t + s], sidx[t + s], svals[t], sidx[t])) {
            svals[t] = svals[t + s]; sidx[t] = sidx[t + s];
        }
        __syncthreads();
    }
    const float gthr = svals[0] + MARGIN_T;
    __syncthreads();
    if (t < 128) {
        if (e.x <= gthr) {
            int p = atomicAdd(&scnt, 1);
            if (p < MAXCAND) scand[p] = __float_as_int(e.y);
        }
        if (e.z <= gthr) {
            int p = atomicAdd(&scnt, 1);
            if (p < MAXCAND) scand[p] = __float_as_int(e.w);
        }
    }
    __syncthreads();
    int m = scnt < MAXCAND ? scnt : MAXCAND;
    if (t < m) {
        int k = scand[t];
        const float* crow = cb + (size_t)k * DIM;
        float acc = 0.0f;
        for (int d = 0; d < DIM; d += 4) {   // exact ascending-d FMA chain
            float4 b = *(const float4*)(crow + d);
            acc = __builtin_fmaf(fr[d + 0], b.x, acc);
            acc = __builtin_fmaf(fr[d + 1], b.y, acc);
            acc = __builtin_fmaf(fr[d + 2], b.z, acc);
            acc = __builtin_fmaf(fr[d + 3], b.w, acc);
        }
        cs[t] = __builtin_fmaf(-2.0f, acc, Srow[n]);
        ck[t] = k;
    }
    __syncthreads();
    if (t == 0) {
        float bv = cs[0]; int bi = ck[0];
        for (int q = 1; q < m; ++q)
            if (lexlt(cs[q], ck[q], bv, bi)) { bv = cs[q]; bi = ck[q]; }
        idxfinal[n] = bi;
    }
}

__global__ void finalize_idx_kernel(const float* __restrict__ lat,
                                    const float* __restrict__ cb,
                                    const int* __restrict__ idxfinal,
                                    float* __restrict__ out_q,
                                    float* __restrict__ out_idx,
                                    float* __restrict__ loss_accum) {
    int n = blockIdx.x;
    int t = threadIdx.x;
    int idx = idxfinal[n];
    const float2 q = ((const float2*)(cb + (size_t)idx * DIM))[t];
    const float2 l = ((const float2*)(lat + (size_t)n * DIM))[t];
    ((float2*)(out_q + (size_t)n * DIM))[t] = q;
    float dx = l.x - q.x, dy = l.y - q.y;
    float local = dx * dx + dy * dy;
    #pragma unroll
    for (int off = 32; off > 0; off >>= 1) local += __shfl_down(local, off);
    __shared__ float wsum[4];
    if ((t & 63) == 0) wsum[t >> 6] = local;
    __syncthreads();
    if (t == 0) {
        atomicAdd(loss_accum, wsum[0] + wsum[1] + wsum[2] + wsum[3]);
        out_idx[n] = (float)idx;
    }
}

// ================= FALLBACK (round-3 verified) =================

__global__ void init_ws_kernel(u64* __restrict__ best, float* __restrict__ loss_accum) {
    int i = blockIdx.x * blockDim.x + threadIdx.x;
    if (i < NROWS) best[i] = 0xFFFFFFFFFFFFFFFFULL;
    if (i == 0) *loss_accum = 0.0f;
}

__global__ __launch_bounds__(256) void dist_argmin_kernel(
        const float* __restrict__ lat, const float* __restrict__ cb,
        const float* __restrict__ Srow, u64* __restrict__ best) {
    __shared__ float As[BD][BM];
    __shared__ float Bs[BD][BN];
    const int tid = threadIdx.x;
    const int tx = tid & 15;
    const int ty = tid >> 4;
    const int row0 = blockIdx.x * BM;
    const int kbase = blockIdx.y * KCHUNK;

    int rowid[8];
    float Sr[8];
    #pragma unroll
    for (int i = 0; i < 8; ++i) {
        rowid[i] = row0 + ((i < 4) ? (ty * 4 + i) : (64 + ty * 4 + (i - 4)));
        Sr[i] = Srow[rowid[i]];
    }
    float bval[8];
    int bidx[8];
    #pragma unroll
    for (int i = 0; i < 8; ++i) { bval[i] = 3.4e38f; bidx[i] = 0; }

    for (int kt = 0; kt < KCHUNK; kt += BN) {
        float acc[8][8];
        #pragma unroll
        for (int i = 0; i < 8; ++i)
            #pragma unroll
            for (int j = 0; j < 8; ++j) acc[i][j] = 0.0f;
        for (int d0 = 0; d0 < DIM; d0 += BD) {
            __syncthreads();
            #pragma unroll
            for (int u = 0; u < 2; ++u) {
                int f = tid * 2 + u;
                int r = f >> 2;
                int dq = (f & 3) * 4;
                float4 va = *(const float4*)(lat + (size_t)(row0 + r) * DIM + d0 + dq);
                As[dq + 0][r] = va.x; As[dq + 1][r] = va.y;
                As[dq + 2][r] = va.z; As[dq + 3][r] = va.w;
                float4 vb = *(const float4*)(cb + (size_t)(kbase + kt + r) * DIM + d0 + dq);
                Bs[dq + 0][r] = vb.x; Bs[dq + 1][r] = vb.y;
                Bs[dq + 2][r] = vb.z; Bs[dq + 3][r] = vb.w;
            }
            __syncthreads();
            #pragma unroll
            for (int dd = 0; dd < BD; ++dd) {
                float4 a0 = *(const float4*)&As[dd][ty * 4];
                float4 a1 = *(const float4*)&As[dd][64 + ty * 4];
                float4 b0 = *(const float4*)&Bs[dd][tx * 4];
                float4 b1 = *(const float4*)&Bs[dd][64 + tx * 4];
                float av[8] = {a0.x, a0.y, a0.z, a0.w, a1.x, a1.y, a1.z, a1.w};
                float bv[8] = {b0.x, b0.y, b0.z, b0.w, b1.x, b1.y, b1.z, b1.w};
                #pragma unroll
                for (int i = 0; i < 8; ++i)
                    #pragma unroll
                    for (int j = 0; j < 8; ++j)
                        acc[i][j] = __builtin_fmaf(av[i], bv[j], acc[i][j]);
            }
        }
        #pragma unroll
        for (int j = 0; j < 8; ++j) {
            int cj = (j < 4) ? (tx * 4 + j) : (64 + tx * 4 + (j - 4));
            int k = kbase + kt + cj;
            #pragma unroll
            for (int i = 0; i < 8; ++i) {
                float s = __builtin_fmaf(-2.0f, acc[i][j], Sr[i]);
                if (s < bval[i]) { bval[i] = s; bidx[i] = k; }
            }
        }
    }
    #pragma unroll
    for (int i = 0; i < 8; ++i) {
        float v = bval[i];
        int ix = bidx[i];
        #pragma unroll
        for (int off = 8; off > 0; off >>= 1) {
            float ov = __shfl_xor(v, off, 16);
            int oi = __shfl_xor(ix, off, 16);
            if (ov < v || (ov == v && oi < ix)) { v = ov; ix = oi; }
        }
        if (tx == 0) {
            unsigned u = __float_as_uint(v);
            unsigned key = (u & 0x80000000u) ? ~u : (u | 0x80000000u);
            u64 pk = ((u64)key << 32) | (unsigned)ix;
            atomicMin(&best[rowid[i]], pk);
        }
    }
}

__global__ void finalize_kernel(const float* __restrict__ lat,
                                const float* __restrict__ cb,
                                const u64* __restrict__ best,
                                float* __restrict__ out_q,
                                float* __restrict__ out_idx,
                                float* __restrict__ loss_accum) {
    int n = blockIdx.x;
    int t = threadIdx.x;
    int idx = (int)(best[n] & 0xFFFFFFFFULL);
    const float2 q = ((const float2*)(cb + (size_t)idx * DIM))[t];
    const float2 l = ((const float2*)(lat + (size_t)n * DIM))[t];
    ((float2*)(out_q + (size_t)n * DIM))[t] = q;
    float dx = l.x - q.x, dy = l.y - q.y;
    float local = dx * dx + dy * dy;
    #pragma unroll
    for (int off = 32; off > 0; off >>= 1) local += __shfl_down(local, off);
    __shared__ float wsum[4];
    if ((t & 63) == 0) wsum[t >> 6] = local;
    __syncthreads();
    if (t == 0) {
        atomicAdd(loss_accum, wsum[0] + wsum[1] + wsum[2] + wsum[3]);
        out_idx[n] = (float)idx;
    }
}

__global__ void write_loss_kernel(const float* __restrict__ loss_accum,
                                  float* __restrict__ out_loss) {
    *out_loss = (1.0f + BETA) * (*loss_accum) * (1.0f / (float)((size_t)NROWS * DIM));
}

// ---------------- launch ----------------

extern "C" void kernel_launch(void* const* d_in, const int* in_sizes, int n_in,
                              void* d_out, int out_size, void* d_ws, size_t ws_size,
                              hipStream_t stream) {
    const float* lat = (const float*)d_in[0];   // [8,1024,512] f32
    const float* cb  = (const float*)d_in[1];   // [8192,512] f32

    float* out = (float*)d_out;
    float* out_q    = out;
    float* out_loss = out + (size_t)NROWS * DIM;
    float* out_idx  = out_loss + 1;

    char* ws = (char*)d_ws;

    // fast-path layout (identical to rounds 4/5 — proven to fit)
    const size_t MATB = (size_t)NROWS * DIM * 2;            // 8 MiB per bf16 matrix
    unsigned short* Ahi = (unsigned short*)(ws);
    unsigned short* Alo = (unsigned short*)(ws + MATB);
    unsigned short* Bhi = (unsigned short*)(ws + 2 * MATB);
    unsigned short* Blo = (unsigned short*)(ws + 3 * MATB);
    float4* top2        = (float4*)(ws + 4 * MATB);         // 16 MiB
    char* tail          = ws + 4 * MATB + (size_t)NROWS * 128 * 16;
    float* SrowF        = (float*)tail;                     // 32 KiB
    int*   idxfinal     = (int*)(tail + 32768);             // 32 KiB
    float* lossF        = (float*)(tail + 65536);           // 4 B
    const size_t REQ    = (size_t)(tail - ws) + 65536 + 64;

    if (ws_size >= REQ) {
        hipLaunchKernelGGL(convert_kernel, dim3(2 * NROWS * DIM / 4 / 256), dim3(256), 0, stream,
                           lat, cb, Ahi, Alo, Bhi, Blo, lossF);
        hipLaunchKernelGGL(rownorm_kernel, dim3(NROWS / 4), dim3(256), 0, stream, lat, SrowF);
        hipLaunchKernelGGL(mfma_dist_kernel, dim3((NROWS / 256) * (KCODES / 256)), dim3(512),
                           0, stream, Ahi, Alo, Bhi, Blo, top2);
        hipLaunchKernelGGL(select_rescore_kernel, dim3(NROWS), dim3(256), 0, stream,
                           lat, cb, SrowF, top2, idxfinal);
        hipLaunchKernelGGL(finalize_idx_kernel, dim3(NROWS), dim3(256), 0, stream,
                           lat, cb, idxfinal, out_q, out_idx, lossF);
        hipLaunchKernelGGL(write_loss_kernel, dim3(1), dim3(1), 0, stream, lossF, out_loss);
    } else {
        // round-3 verified fallback
        u64*   best       = (u64*)(ws + 0);
        float* Srow       = (float*)(ws + 65536);
        float* loss_accum = (float*)(ws + 98304);
        hipLaunchKernelGGL(init_ws_kernel, dim3(32), dim3(256), 0, stream, best, loss_accum);
        hipLaunchKernelGGL(rownorm_kernel, dim3(NROWS / 4), dim3(256), 0, stream, lat, Srow);
        hipLaunchKernelGGL(dist_argmin_kernel, dim3(NROWS / BM, KCODES / KCHUNK), dim3(256),
                           0, stream, lat, cb, Srow, best);
        hipLaunchKernelGGL(finalize_kernel, dim3(NROWS), dim3(256), 0, stream,
                           lat, cb, best, out_q, out_idx, loss_accum);
        hipLaunchKernelGGL(write_loss_kernel, dim3(1), dim3(1), 0, stream, loss_accum, out_loss);
    }
}

// Round 8
// 767.981 us; speedup vs baseline: 1.1521x; 1.1472x over previous
//
#include <hip/hip_runtime.h>
#include <stdint.h>

#define NROWS 8192
#define KCODES 8192
#define DIM 512
#define BETA 0.25f

// fallback fp32 path tiling
#define BM 128
#define BN 128
#define BD 16
#define KCHUNK 512

// fast path: hi*hi screen error <= ~4e-4 worst-case; margin = 2x
#define MARGIN_T 8.0e-4f
#define MAXCAND 32

typedef unsigned long long u64;
typedef __attribute__((ext_vector_type(8))) short bf16x8;
typedef __attribute__((ext_vector_type(4))) float f32x4;
typedef __attribute__((ext_vector_type(4))) unsigned short us4;

// ---------------- shared helpers ----------------

__device__ inline unsigned short f2bf_rne(float x) {
    union { float f; unsigned u; } v; v.f = x;
    unsigned r = v.u + 0x7FFFu + ((v.u >> 16) & 1u);
    return (unsigned short)(r >> 16);
}
__device__ inline bool lexlt(float av, int ai, float bv, int bi) {
    return (av < bv) || (av == bv && ai < bi);
}
__device__ inline void ins2(float& v1, int& i1, float& v2, int& i2, float nv, int ni) {
    if (lexlt(nv, ni, v1, i1)) { v2 = v1; i2 = i1; v1 = nv; i1 = ni; }
    else if (lexlt(nv, ni, v2, i2)) { v2 = nv; i2 = ni; }
}
__device__ inline void gload_lds16(const void* g, void* l) {
    __builtin_amdgcn_global_load_lds(
        (const __attribute__((address_space(1))) void*)g,
        (__attribute__((address_space(3))) void*)l, 16, 0, 0);
}

// ---------------- common: numpy-exact row norm ----------------
__global__ __launch_bounds__(256) void rownorm_kernel(const float* __restrict__ lat,
                                                      float* __restrict__ Srow) {
    __shared__ float buf[4][DIM];
    const int w = threadIdx.x >> 6;
    const int lane = threadIdx.x & 63;
    const int n = blockIdx.x * 4 + w;
    {
        const float4* p = (const float4*)(lat + (size_t)n * DIM);
        float4 v0 = p[lane * 2];
        float4 v1 = p[lane * 2 + 1];
        float4* q = (float4*)buf[w];
        q[lane * 2] = v0;
        q[lane * 2 + 1] = v1;
    }
    __syncthreads();
    if (lane < 32) {
        const int m = lane >> 3;
        const int j = lane & 7;
        const float* b = buf[w] + 128 * m + j;
        float r = b[0] * b[0];
        #pragma unroll
        for (int t = 1; t < 16; ++t) { float x = b[8 * t]; r += x * x; }
        float s1 = r + __shfl_down(r, 1);
        float s2 = s1 + __shfl_down(s1, 2);
        float s3 = s2 + __shfl_down(s2, 4);
        float x0 = s3 + __shfl_down(s3, 8);
        float S = x0 + __shfl_down(x0, 16);
        if (lane == 0) Srow[n] = S;
    }
}

// ================= FAST PATH =================

// f32 -> bf16 (hi only; rescore uses the fp32 originals)
__global__ __launch_bounds__(256) void convert_kernel(
        const float* __restrict__ lat, const float* __restrict__ cb,
        unsigned short* __restrict__ Ahi, unsigned short* __restrict__ Bhi,
        float* __restrict__ loss_accum) {
    size_t i = (size_t)blockIdx.x * 256 + threadIdx.x;
    if (i == 0) *loss_accum = 0.0f;
    const size_t half = (size_t)NROWS * DIM / 4;
    const float* src; unsigned short* hi;
    if (i < half) { src = lat; hi = Ahi; }
    else { src = cb; hi = Bhi; i -= half; }
    float4 v = ((const float4*)src)[i];
    us4 h;
    h.x = f2bf_rne(v.x);
    h.y = f2bf_rne(v.y);
    h.z = f2bf_rne(v.z);
    h.w = f2bf_rne(v.w);
    *(us4*)&hi[i * 4] = h;
}

// 256x256 tile, BK=64, 8 K-steps, 8 waves (2x4), double-buffered LDS with
// stage-before-compute prefetch and plain __syncthreads() (round-5 proven
// deterministic structure). Screen = hi*hi product only (err <= ~4e-4,
// absorbed by MARGIN_T + exact rescore). Supertiled XCD mapping.
__global__ __launch_bounds__(512) void mfma_dist_kernel(
        const unsigned short* __restrict__ Ahi, const unsigned short* __restrict__ Bhi,
        float4* __restrict__ top2) {
    __shared__ unsigned short sA[2][256][64];   // 64 KiB
    __shared__ unsigned short sB[2][256][64];   // 64 KiB
    const int bid = blockIdx.x;
    const int xcd = bid & 7;
    const int j = bid >> 3;
    const int st = j >> 4;
    const int tt = j & 15;
    const int bx = st * 4 + (tt & 3);
    const int by = xcd * 4 + (tt >> 2);
    const int row0 = bx * 256, col0 = by * 256;
    const int tid = threadIdx.x;
    const int w = tid >> 6, l = tid & 63;
    const int wm = w >> 2, wn = w & 3;
    const int g = l >> 4, c = l & 15;

    f32x4 acc[8][4];
    #pragma unroll
    for (int a = 0; a < 8; ++a)
        #pragma unroll
        for (int b = 0; b < 4; ++b)
            acc[a][b] = (f32x4){0.f, 0.f, 0.f, 0.f};

    const int lr = l >> 3;
    const int lc = l & 7;

    auto stage = [&](int bsel, int kt) {
        const int d0 = kt * 64;
        #pragma unroll
        for (int i = 0; i < 4; ++i) {
            const int r0 = w * 32 + i * 8;
            const int r = r0 + lr;
            const int chunk = lc ^ (r & 7);     // pre-swizzled global source
            gload_lds16(Ahi + (size_t)(row0 + r) * DIM + d0 + chunk * 8,
                        &sA[bsel][r0][0]);
            gload_lds16(Bhi + (size_t)(col0 + r) * DIM + d0 + chunk * 8,
                        &sB[bsel][r0][0]);
        }
    };

    auto compute = [&](int bsel) {
        #pragma unroll
        for (int kk = 0; kk < 2; ++kk) {
            const int colbase = kk * 32 + g * 8;
            bf16x8 af[8], bfr[4];
            #pragma unroll
            for (int f = 0; f < 8; ++f) {
                int ra = wm * 128 + f * 16 + c;
                int ca = colbase ^ ((ra & 7) << 3);
                af[f] = *(const bf16x8*)&sA[bsel][ra][ca];
            }
            #pragma unroll
            for (int f = 0; f < 4; ++f) {
                int rb = wn * 64 + f * 16 + c;
                int cb2 = colbase ^ ((rb & 7) << 3);
                bfr[f] = *(const bf16x8*)&sB[bsel][rb][cb2];
            }
            #pragma unroll
            for (int fm = 0; fm < 8; ++fm)
                #pragma unroll
                for (int fn = 0; fn < 4; ++fn)
                    acc[fm][fn] = __builtin_amdgcn_mfma_f32_16x16x32_bf16(
                        af[fm], bfr[fn], acc[fm][fn], 0, 0, 0);
        }
    };

    stage(0, 0);
    __syncthreads();                 // full drain: buf0 staged and visible
    int cur = 0;
    for (int kt = 0; kt < 8; ++kt) {
        if (kt < 7) stage(cur ^ 1, kt + 1);   // prefetch overlaps compute window
        compute(cur);
        __syncthreads();             // drains vmcnt+lgkm; next tile ready, cur reusable
        cur ^= 1;
    }

    // epilogue: per-row top-2 over this wave's 64 codes (lex (t,idx)); t=-2*acc
    #pragma unroll
    for (int fm = 0; fm < 8; ++fm) {
        #pragma unroll
        for (int r = 0; r < 4; ++r) {
            float v1 = -2.0f * acc[fm][0][r];
            int i1 = col0 + wn * 64 + c;
            float v2 = 3.4e38f; int i2 = 0x7FFFFFFF;
            #pragma unroll
            for (int fn = 1; fn < 4; ++fn) {
                float nv = -2.0f * acc[fm][fn][r];
                int ni = col0 + wn * 64 + fn * 16 + c;
                ins2(v1, i1, v2, i2, nv, ni);
            }
            #pragma unroll
            for (int mask = 1; mask <= 8; mask <<= 1) {
                float o1 = __shfl_xor(v1, mask); int oi1 = __shfl_xor(i1, mask);
                float o2 = __shfl_xor(v2, mask); int oi2 = __shfl_xor(i2, mask);
                ins2(v1, i1, v2, i2, o1, oi1);
                ins2(v1, i1, v2, i2, o2, oi2);
            }
            if (c == 0) {
                int row = row0 + wm * 128 + fm * 16 + g * 4 + r;
                float4 e;
                e.x = v1; e.y = __int_as_float(i1);
                e.z = v2; e.w = __int_as_float(i2);
                top2[(size_t)row * 128 + by * 4 + wn] = e;
            }
        }
    }
}

// per row: global approx min over 256 stored entries, margin candidates,
// exact numpy-fp32-chain rescore, lexicographic winner.
__global__ __launch_bounds__(256) void select_rescore_kernel(
        const float* __restrict__ lat, const float* __restrict__ cb,
        const float* __restrict__ Srow, const float4* __restrict__ top2,
        int* __restrict__ idxfinal) {
    __shared__ float fr[DIM];
    __shared__ float svals[128];
    __shared__ int sidx[128];
    __shared__ int scnt;
    __shared__ int scand[MAXCAND];
    __shared__ float cs[MAXCAND];
    __shared__ int ck[MAXCAND];
    const int n = blockIdx.x;
    const int t = threadIdx.x;

    fr[t] = lat[(size_t)n * DIM + t];
    fr[t + 256] = lat[(size_t)n * DIM + t + 256];
    if (t == 0) scnt = 0;

    float4 e;
    if (t < 128) {
        e = top2[(size_t)n * 128 + t];
        float pv = e.x; int pi = __float_as_int(e.y);
        int e2 = __float_as_int(e.w);
        if (lexlt(e.z, e2, pv, pi)) { pv = e.z; pi = e2; }
        svals[t] = pv; sidx[t] = pi;
    }
    __syncthreads();
    for (int s = 64; s > 0; s >>= 1) {
        if (t < s && lexlt(svals[t + s], sidx[t + s], svals[t], sidx[t])) {
            svals[t] = svals[t + s]; sidx[t] = sidx[t + s];
        }
        __syncthreads();
    }
    const float gthr = svals[0] + MARGIN_T;
    __syncthreads();
    if (t < 128) {
        if (e.x <= gthr) {
            int p = atomicAdd(&scnt, 1);
            if (p < MAXCAND) scand[p] = __float_as_int(e.y);
        }
        if (e.z <= gthr) {
            int p = atomicAdd(&scnt, 1);
            if (p < MAXCAND) scand[p] = __float_as_int(e.w);
        }
    }
    __syncthreads();
    int m = scnt < MAXCAND ? scnt : MAXCAND;
    if (t < m) {
        int k = scand[t];
        const float* crow = cb + (size_t)k * DIM;
        float acc = 0.0f;
        for (int d = 0; d < DIM; d += 4) {   // exact ascending-d FMA chain
            float4 b = *(const float4*)(crow + d);
            acc = __builtin_fmaf(fr[d + 0], b.x, acc);
            acc = __builtin_fmaf(fr[d + 1], b.y, acc);
            acc = __builtin_fmaf(fr[d + 2], b.z, acc);
            acc = __builtin_fmaf(fr[d + 3], b.w, acc);
        }
        cs[t] = __builtin_fmaf(-2.0f, acc, Srow[n]);
        ck[t] = k;
    }
    __syncthreads();
    if (t == 0) {
        float bv = cs[0]; int bi = ck[0];
        for (int q = 1; q < m; ++q)
            if (lexlt(cs[q], ck[q], bv, bi)) { bv = cs[q]; bi = ck[q]; }
        idxfinal[n] = bi;
    }
}

__global__ void finalize_idx_kernel(const float* __restrict__ lat,
                                    const float* __restrict__ cb,
                                    const int* __restrict__ idxfinal,
                                    float* __restrict__ out_q,
                                    float* __restrict__ out_idx,
                                    float* __restrict__ loss_accum) {
    int n = blockIdx.x;
    int t = threadIdx.x;
    int idx = idxfinal[n];
    const float2 q = ((const float2*)(cb + (size_t)idx * DIM))[t];
    const float2 l = ((const float2*)(lat + (size_t)n * DIM))[t];
    ((float2*)(out_q + (size_t)n * DIM))[t] = q;
    float dx = l.x - q.x, dy = l.y - q.y;
    float local = dx * dx + dy * dy;
    #pragma unroll
    for (int off = 32; off > 0; off >>= 1) local += __shfl_down(local, off);
    __shared__ float wsum[4];
    if ((t & 63) == 0) wsum[t >> 6] = local;
    __syncthreads();
    if (t == 0) {
        atomicAdd(loss_accum, wsum[0] + wsum[1] + wsum[2] + wsum[3]);
        out_idx[n] = (float)idx;
    }
}

// ================= FALLBACK (round-3 verified) =================

__global__ void init_ws_kernel(u64* __restrict__ best, float* __restrict__ loss_accum) {
    int i = blockIdx.x * blockDim.x + threadIdx.x;
    if (i < NROWS) best[i] = 0xFFFFFFFFFFFFFFFFULL;
    if (i == 0) *loss_accum = 0.0f;
}

__global__ __launch_bounds__(256) void dist_argmin_kernel(
        const float* __restrict__ lat, const float* __restrict__ cb,
        const float* __restrict__ Srow, u64* __restrict__ best) {
    __shared__ float As[BD][BM];
    __shared__ float Bs[BD][BN];
    const int tid = threadIdx.x;
    const int tx = tid & 15;
    const int ty = tid >> 4;
    const int row0 = blockIdx.x * BM;
    const int kbase = blockIdx.y * KCHUNK;

    int rowid[8];
    float Sr[8];
    #pragma unroll
    for (int i = 0; i < 8; ++i) {
        rowid[i] = row0 + ((i < 4) ? (ty * 4 + i) : (64 + ty * 4 + (i - 4)));
        Sr[i] = Srow[rowid[i]];
    }
    float bval[8];
    int bidx[8];
    #pragma unroll
    for (int i = 0; i < 8; ++i) { bval[i] = 3.4e38f; bidx[i] = 0; }

    for (int kt = 0; kt < KCHUNK; kt += BN) {
        float acc[8][8];
        #pragma unroll
        for (int i = 0; i < 8; ++i)
            #pragma unroll
            for (int j = 0; j < 8; ++j) acc[i][j] = 0.0f;
        for (int d0 = 0; d0 < DIM; d0 += BD) {
            __syncthreads();
            #pragma unroll
            for (int u = 0; u < 2; ++u) {
                int f = tid * 2 + u;
                int r = f >> 2;
                int dq = (f & 3) * 4;
                float4 va = *(const float4*)(lat + (size_t)(row0 + r) * DIM + d0 + dq);
                As[dq + 0][r] = va.x; As[dq + 1][r] = va.y;
                As[dq + 2][r] = va.z; As[dq + 3][r] = va.w;
                float4 vb = *(const float4*)(cb + (size_t)(kbase + kt + r) * DIM + d0 + dq);
                Bs[dq + 0][r] = vb.x; Bs[dq + 1][r] = vb.y;
                Bs[dq + 2][r] = vb.z; Bs[dq + 3][r] = vb.w;
            }
            __syncthreads();
            #pragma unroll
            for (int dd = 0; dd < BD; ++dd) {
                float4 a0 = *(const float4*)&As[dd][ty * 4];
                float4 a1 = *(const float4*)&As[dd][64 + ty * 4];
                float4 b0 = *(const float4*)&Bs[dd][tx * 4];
                float4 b1 = *(const float4*)&Bs[dd][64 + tx * 4];
                float av[8] = {a0.x, a0.y, a0.z, a0.w, a1.x, a1.y, a1.z, a1.w};
                float bv[8] = {b0.x, b0.y, b0.z, b0.w, b1.x, b1.y, b1.z, b1.w};
                #pragma unroll
                for (int i = 0; i < 8; ++i)
                    #pragma unroll
                    for (int j = 0; j < 8; ++j)
                        acc[i][j] = __builtin_fmaf(av[i], bv[j], acc[i][j]);
            }
        }
        #pragma unroll
        for (int j = 0; j < 8; ++j) {
            int cj = (j < 4) ? (tx * 4 + j) : (64 + tx * 4 + (j - 4));
            int k = kbase + kt + cj;
            #pragma unroll
            for (int i = 0; i < 8; ++i) {
                float s = __builtin_fmaf(-2.0f, acc[i][j], Sr[i]);
                if (s < bval[i]) { bval[i] = s; bidx[i] = k; }
            }
        }
    }
    #pragma unroll
    for (int i = 0; i < 8; ++i) {
        float v = bval[i];
        int ix = bidx[i];
        #pragma unroll
        for (int off = 8; off > 0; off >>= 1) {
            float ov = __shfl_xor(v, off, 16);
            int oi = __shfl_xor(ix, off, 16);
            if (ov < v || (ov == v && oi < ix)) { v = ov; ix = oi; }
        }
        if (tx == 0) {
            unsigned u = __float_as_uint(v);
            unsigned key = (u & 0x80000000u) ? ~u : (u | 0x80000000u);
            u64 pk = ((u64)key << 32) | (unsigned)ix;
            atomicMin(&best[rowid[i]], pk);
        }
    }
}

__global__ void finalize_kernel(const float* __restrict__ lat,
                                const float* __restrict__ cb,
                                const u64* __restrict__ best,
                                float* __restrict__ out_q,
                                float* __restrict__ out_idx,
                                float* __restrict__ loss_accum) {
    int n = blockIdx.x;
    int t = threadIdx.x;
    int idx = (int)(best[n] & 0xFFFFFFFFULL);
    const float2 q = ((const float2*)(cb + (size_t)idx * DIM))[t];
    const float2 l = ((const float2*)(lat + (size_t)n * DIM))[t];
    ((float2*)(out_q + (size_t)n * DIM))[t] = q;
    float dx = l.x - q.x, dy = l.y - q.y;
    float local = dx * dx + dy * dy;
    #pragma unroll
    for (int off = 32; off > 0; off >>= 1) local += __shfl_down(local, off);
    __shared__ float wsum[4];
    if ((t & 63) == 0) wsum[t >> 6] = local;
    __syncthreads();
    if (t == 0) {
        atomicAdd(loss_accum, wsum[0] + wsum[1] + wsum[2] + wsum[3]);
        out_idx[n] = (float)idx;
    }
}

__global__ void write_loss_kernel(const float* __restrict__ loss_accum,
                                  float* __restrict__ out_loss) {
    *out_loss = (1.0f + BETA) * (*loss_accum) * (1.0f / (float)((size_t)NROWS * DIM));
}

// ---------------- launch ----------------

extern "C" void kernel_launch(void* const* d_in, const int* in_sizes, int n_in,
                              void* d_out, int out_size, void* d_ws, size_t ws_size,
                              hipStream_t stream) {
    const float* lat = (const float*)d_in[0];   // [8,1024,512] f32
    const float* cb  = (const float*)d_in[1];   // [8192,512] f32

    float* out = (float*)d_out;
    float* out_q    = out;
    float* out_loss = out + (size_t)NROWS * DIM;
    float* out_idx  = out_loss + 1;

    char* ws = (char*)d_ws;

    // fast-path layout
    const size_t MATB = (size_t)NROWS * DIM * 2;            // 8 MiB per bf16 matrix
    unsigned short* Ahi = (unsigned short*)(ws);
    unsigned short* Bhi = (unsigned short*)(ws + MATB);
    float4* top2        = (float4*)(ws + 2 * MATB);         // 16 MiB
    char* tail          = ws + 2 * MATB + (size_t)NROWS * 128 * 16;
    float* SrowF        = (float*)tail;                     // 32 KiB
    int*   idxfinal     = (int*)(tail + 32768);             // 32 KiB
    float* lossF        = (float*)(tail + 65536);           // 4 B
    const size_t REQ    = (size_t)(tail - ws) + 65536 + 64;

    if (ws_size >= REQ) {
        hipLaunchKernelGGL(convert_kernel, dim3(2 * NROWS * DIM / 4 / 256), dim3(256), 0, stream,
                           lat, cb, Ahi, Bhi, lossF);
        hipLaunchKernelGGL(rownorm_kernel, dim3(NROWS / 4), dim3(256), 0, stream, lat, SrowF);
        hipLaunchKernelGGL(mfma_dist_kernel, dim3((NROWS / 256) * (KCODES / 256)), dim3(512),
                           0, stream, Ahi, Bhi, top2);
        hipLaunchKernelGGL(select_rescore_kernel, dim3(NROWS), dim3(256), 0, stream,
                           lat, cb, SrowF, top2, idxfinal);
        hipLaunchKernelGGL(finalize_idx_kernel, dim3(NROWS), dim3(256), 0, stream,
                           lat, cb, idxfinal, out_q, out_idx, lossF);
        hipLaunchKernelGGL(write_loss_kernel, dim3(1), dim3(1), 0, stream, lossF, out_loss);
    } else {
        // round-3 verified fallback
        u64*   best       = (u64*)(ws + 0);
        float* Srow       = (float*)(ws + 65536);
        float* loss_accum = (float*)(ws + 98304);
        hipLaunchKernelGGL(init_ws_kernel, dim3(32), dim3(256), 0, stream, best, loss_accum);
        hipLaunchKernelGGL(rownorm_kernel, dim3(NROWS / 4), dim3(256), 0, stream, lat, Srow);
        hipLaunchKernelGGL(dist_argmin_kernel, dim3(NROWS / BM, KCODES / KCHUNK), dim3(256),
                           0, stream, lat, cb, Srow, best);
        hipLaunchKernelGGL(finalize_kernel, dim3(NROWS), dim3(256), 0, stream,
                           lat, cb, best, out_q, out_idx, loss_accum);
        hipLaunchKernelGGL(write_loss_kernel, dim3(1), dim3(1), 0, stream, loss_accum, out_loss);
    }
}

// Round 9
// 725.442 us; speedup vs baseline: 1.2197x; 1.0586x over previous
//
#include <hip/hip_runtime.h>
#include <stdint.h>

#define NROWS 8192
#define KCODES 8192
#define DIM 512
#define BETA 0.25f

// fallback fp32 path tiling
#define BM 128
#define BN 128
#define BD 16
#define KCHUNK 512

// fast path: hi*hi screen error <= ~4e-4 worst-case; margin = 2x
#define MARGIN_T 8.0e-4f
#define MAXCAND 32

typedef unsigned long long u64;
typedef __attribute__((ext_vector_type(8))) short bf16x8;
typedef __attribute__((ext_vector_type(4))) float f32x4;
typedef __attribute__((ext_vector_type(4))) unsigned short us4;

// ---------------- shared helpers ----------------

__device__ inline unsigned short f2bf_rne(float x) {
    union { float f; unsigned u; } v; v.f = x;
    unsigned r = v.u + 0x7FFFu + ((v.u >> 16) & 1u);
    return (unsigned short)(r >> 16);
}
__device__ inline bool lexlt(float av, int ai, float bv, int bi) {
    return (av < bv) || (av == bv && ai < bi);
}
__device__ inline void ins2(float& v1, int& i1, float& v2, int& i2, float nv, int ni) {
    if (lexlt(nv, ni, v1, i1)) { v2 = v1; i2 = i1; v1 = nv; i1 = ni; }
    else if (lexlt(nv, ni, v2, i2)) { v2 = nv; i2 = ni; }
}
__device__ inline void gload_lds16(const void* g, void* l) {
    __builtin_amdgcn_global_load_lds(
        (const __attribute__((address_space(1))) void*)g,
        (__attribute__((address_space(3))) void*)l, 16, 0, 0);
}

// ---------------- common: numpy-exact row norm ----------------
__global__ __launch_bounds__(256) void rownorm_kernel(const float* __restrict__ lat,
                                                      float* __restrict__ Srow) {
    __shared__ float buf[4][DIM];
    const int w = threadIdx.x >> 6;
    const int lane = threadIdx.x & 63;
    const int n = blockIdx.x * 4 + w;
    {
        const float4* p = (const float4*)(lat + (size_t)n * DIM);
        float4 v0 = p[lane * 2];
        float4 v1 = p[lane * 2 + 1];
        float4* q = (float4*)buf[w];
        q[lane * 2] = v0;
        q[lane * 2 + 1] = v1;
    }
    __syncthreads();
    if (lane < 32) {
        const int m = lane >> 3;
        const int j = lane & 7;
        const float* b = buf[w] + 128 * m + j;
        float r = b[0] * b[0];
        #pragma unroll
        for (int t = 1; t < 16; ++t) { float x = b[8 * t]; r += x * x; }
        float s1 = r + __shfl_down(r, 1);
        float s2 = s1 + __shfl_down(s1, 2);
        float s3 = s2 + __shfl_down(s2, 4);
        float x0 = s3 + __shfl_down(s3, 8);
        float S = x0 + __shfl_down(x0, 16);
        if (lane == 0) Srow[n] = S;
    }
}

// ================= FAST PATH =================

// f32 -> bf16 (hi only; rescore uses the fp32 originals)
__global__ __launch_bounds__(256) void convert_kernel(
        const float* __restrict__ lat, const float* __restrict__ cb,
        unsigned short* __restrict__ Ahi, unsigned short* __restrict__ Bhi,
        float* __restrict__ loss_accum) {
    size_t i = (size_t)blockIdx.x * 256 + threadIdx.x;
    if (i == 0) *loss_accum = 0.0f;
    const size_t half = (size_t)NROWS * DIM / 4;
    const float* src; unsigned short* hi;
    if (i < half) { src = lat; hi = Ahi; }
    else { src = cb; hi = Bhi; i -= half; }
    float4 v = ((const float4*)src)[i];
    us4 h;
    h.x = f2bf_rne(v.x);
    h.y = f2bf_rne(v.y);
    h.z = f2bf_rne(v.z);
    h.w = f2bf_rne(v.w);
    *(us4*)&hi[i * 4] = h;
}

// m97-structure port: 128x128 tile, BK=64, 4 waves (2x2, 64x64 each),
// SINGLE-buffered 32 KiB LDS, 2-barrier loop, 4 blocks/CU for inter-block
// barrier-drain overlap (m114 mechanism). Screen = hi*hi bf16 product
// (err <= ~4e-4, absorbed by MARGIN_T + exact rescore). Per-wave per-row
// top-2 over its 64 codes -> top2[row][by*2+wn] (same layout as before).
__global__ __launch_bounds__(256, 4) void mfma_dist_kernel(
        const unsigned short* __restrict__ Ahi, const unsigned short* __restrict__ Bhi,
        float4* __restrict__ top2) {
    __shared__ unsigned short sA[128][64];   // 16 KiB
    __shared__ unsigned short sB[128][64];   // 16 KiB
    // XCD supertile mapping: xcd = bid&7 owns by in [xcd*8, xcd*8+8);
    // bx swept in groups of 4 -> per-XCD resident set ~3 MB (fits 4 MB L2).
    const int bid = blockIdx.x;
    const int xcd = bid & 7;
    const int j = bid >> 3;            // 0..511
    const int gg = j >> 5;             // 0..15
    const int u = j & 31;
    const int bx = gg * 4 + (u & 3);   // 0..63
    const int by = xcd * 8 + (u >> 2); // 0..63
    const int row0 = bx * 128, col0 = by * 128;
    const int tid = threadIdx.x;
    const int w = tid >> 6, l = tid & 63;
    const int wm = w >> 1, wn = w & 1;          // 2x2 wave grid
    const int g = l >> 4, c = l & 15;

    f32x4 acc[4][4];
    #pragma unroll
    for (int a = 0; a < 4; ++a)
        #pragma unroll
        for (int b = 0; b < 4; ++b)
            acc[a][b] = (f32x4){0.f, 0.f, 0.f, 0.f};

    const int lr = l >> 3;          // lane row within 8-row stripe
    const int lc = l & 7;           // lane col-chunk

    for (int kt = 0; kt < 8; ++kt) {
        const int d0 = kt * 64;
        // stage: LDS linear dest, pre-swizzled global source (involution)
        #pragma unroll
        for (int i = 0; i < 4; ++i) {
            const int r0 = w * 32 + i * 8;
            const int r = r0 + lr;
            const int chunk = lc ^ (r & 7);
            gload_lds16(Ahi + (size_t)(row0 + r) * DIM + d0 + chunk * 8,
                        &sA[r0][0]);
            gload_lds16(Bhi + (size_t)(col0 + r) * DIM + d0 + chunk * 8,
                        &sB[r0][0]);
        }
        __syncthreads();   // drain: tile staged and visible
        #pragma unroll
        for (int kk = 0; kk < 2; ++kk) {
            const int colbase = kk * 32 + g * 8;
            bf16x8 af[4], bfr[4];
            #pragma unroll
            for (int f = 0; f < 4; ++f) {
                int ra = wm * 64 + f * 16 + c;
                int ca = colbase ^ ((ra & 7) << 3);   // swizzled read
                af[f] = *(const bf16x8*)&sA[ra][ca];
                int rb = wn * 64 + f * 16 + c;
                int cb2 = colbase ^ ((rb & 7) << 3);
                bfr[f] = *(const bf16x8*)&sB[rb][cb2];
            }
            #pragma unroll
            for (int fm = 0; fm < 4; ++fm)
                #pragma unroll
                for (int fn = 0; fn < 4; ++fn)
                    acc[fm][fn] = __builtin_amdgcn_mfma_f32_16x16x32_bf16(
                        af[fm], bfr[fn], acc[fm][fn], 0, 0, 0);
        }
        __syncthreads();   // all reads done; safe to overwrite next step
    }

    // epilogue: per-row top-2 over this wave's 64 codes (lex (t,idx)); t=-2*acc
    #pragma unroll
    for (int fm = 0; fm < 4; ++fm) {
        #pragma unroll
        for (int r = 0; r < 4; ++r) {
            float v1 = -2.0f * acc[fm][0][r];
            int i1 = col0 + wn * 64 + c;
            float v2 = 3.4e38f; int i2 = 0x7FFFFFFF;
            #pragma unroll
            for (int fn = 1; fn < 4; ++fn) {
                float nv = -2.0f * acc[fm][fn][r];
                int ni = col0 + wn * 64 + fn * 16 + c;
                ins2(v1, i1, v2, i2, nv, ni);
            }
            #pragma unroll
            for (int mask = 1; mask <= 8; mask <<= 1) {
                float o1 = __shfl_xor(v1, mask); int oi1 = __shfl_xor(i1, mask);
                float o2 = __shfl_xor(v2, mask); int oi2 = __shfl_xor(i2, mask);
                ins2(v1, i1, v2, i2, o1, oi1);
                ins2(v1, i1, v2, i2, o2, oi2);
            }
            if (c == 0) {
                int row = row0 + wm * 64 + fm * 16 + g * 4 + r;
                float4 e;
                e.x = v1; e.y = __int_as_float(i1);
                e.z = v2; e.w = __int_as_float(i2);
                top2[(size_t)row * 128 + by * 2 + wn] = e;
            }
        }
    }
}

// per row: global approx min over 256 stored entries, margin candidates,
// exact numpy-fp32-chain rescore, lexicographic winner.
__global__ __launch_bounds__(256) void select_rescore_kernel(
        const float* __restrict__ lat, const float* __restrict__ cb,
        const float* __restrict__ Srow, const float4* __restrict__ top2,
        int* __restrict__ idxfinal) {
    __shared__ float fr[DIM];
    __shared__ float svals[128];
    __shared__ int sidx[128];
    __shared__ int scnt;
    __shared__ int scand[MAXCAND];
    __shared__ float cs[MAXCAND];
    __shared__ int ck[MAXCAND];
    const int n = blockIdx.x;
    const int t = threadIdx.x;

    fr[t] = lat[(size_t)n * DIM + t];
    fr[t + 256] = lat[(size_t)n * DIM + t + 256];
    if (t == 0) scnt = 0;

    float4 e;
    if (t < 128) {
        e = top2[(size_t)n * 128 + t];
        float pv = e.x; int pi = __float_as_int(e.y);
        int e2 = __float_as_int(e.w);
        if (lexlt(e.z, e2, pv, pi)) { pv = e.z; pi = e2; }
        svals[t] = pv; sidx[t] = pi;
    }
    __syncthreads();
    for (int s = 64; s > 0; s >>= 1) {
        if (t < s && lexlt(svals[t + s], sidx[t + s], svals[t], sidx[t])) {
            svals[t] = svals[t + s]; sidx[t] = sidx[t + s];
        }
        __syncthreads();
    }
    const float gthr = svals[0] + MARGIN_T;
    __syncthreads();
    if (t < 128) {
        if (e.x <= gthr) {
            int p = atomicAdd(&scnt, 1);
            if (p < MAXCAND) scand[p] = __float_as_int(e.y);
        }
        if (e.z <= gthr) {
            int p = atomicAdd(&scnt, 1);
            if (p < MAXCAND) scand[p] = __float_as_int(e.w);
        }
    }
    __syncthreads();
    int m = scnt < MAXCAND ? scnt : MAXCAND;
    if (t < m) {
        int k = scand[t];
        const float* crow = cb + (size_t)k * DIM;
        float acc = 0.0f;
        for (int d = 0; d < DIM; d += 4) {   // exact ascending-d FMA chain
            float4 b = *(const float4*)(crow + d);
            acc = __builtin_fmaf(fr[d + 0], b.x, acc);
            acc = __builtin_fmaf(fr[d + 1], b.y, acc);
            acc = __builtin_fmaf(fr[d + 2], b.z, acc);
            acc = __builtin_fmaf(fr[d + 3], b.w, acc);
        }
        cs[t] = __builtin_fmaf(-2.0f, acc, Srow[n]);
        ck[t] = k;
    }
    __syncthreads();
    if (t == 0) {
        float bv = cs[0]; int bi = ck[0];
        for (int q = 1; q < m; ++q)
            if (lexlt(cs[q], ck[q], bv, bi)) { bv = cs[q]; bi = ck[q]; }
        idxfinal[n] = bi;
    }
}

__global__ void finalize_idx_kernel(const float* __restrict__ lat,
                                    const float* __restrict__ cb,
                                    const int* __restrict__ idxfinal,
                                    float* __restrict__ out_q,
                                    float* __restrict__ out_idx,
                                    float* __restrict__ loss_accum) {
    int n = blockIdx.x;
    int t = threadIdx.x;
    int idx = idxfinal[n];
    const float2 q = ((const float2*)(cb + (size_t)idx * DIM))[t];
    const float2 l = ((const float2*)(lat + (size_t)n * DIM))[t];
    ((float2*)(out_q + (size_t)n * DIM))[t] = q;
    float dx = l.x - q.x, dy = l.y - q.y;
    float local = dx * dx + dy * dy;
    #pragma unroll
    for (int off = 32; off > 0; off >>= 1) local += __shfl_down(local, off);
    __shared__ float wsum[4];
    if ((t & 63) == 0) wsum[t >> 6] = local;
    __syncthreads();
    if (t == 0) {
        atomicAdd(loss_accum, wsum[0] + wsum[1] + wsum[2] + wsum[3]);
        out_idx[n] = (float)idx;
    }
}

// ================= FALLBACK (round-3 verified) =================

__global__ void init_ws_kernel(u64* __restrict__ best, float* __restrict__ loss_accum) {
    int i = blockIdx.x * blockDim.x + threadIdx.x;
    if (i < NROWS) best[i] = 0xFFFFFFFFFFFFFFFFULL;
    if (i == 0) *loss_accum = 0.0f;
}

__global__ __launch_bounds__(256) void dist_argmin_kernel(
        const float* __restrict__ lat, const float* __restrict__ cb,
        const float* __restrict__ Srow, u64* __restrict__ best) {
    __shared__ float As[BD][BM];
    __shared__ float Bs[BD][BN];
    const int tid = threadIdx.x;
    const int tx = tid & 15;
    const int ty = tid >> 4;
    const int row0 = blockIdx.x * BM;
    const int kbase = blockIdx.y * KCHUNK;

    int rowid[8];
    float Sr[8];
    #pragma unroll
    for (int i = 0; i < 8; ++i) {
        rowid[i] = row0 + ((i < 4) ? (ty * 4 + i) : (64 + ty * 4 + (i - 4)));
        Sr[i] = Srow[rowid[i]];
    }
    float bval[8];
    int bidx[8];
    #pragma unroll
    for (int i = 0; i < 8; ++i) { bval[i] = 3.4e38f; bidx[i] = 0; }

    for (int kt = 0; kt < KCHUNK; kt += BN) {
        float acc[8][8];
        #pragma unroll
        for (int i = 0; i < 8; ++i)
            #pragma unroll
            for (int j = 0; j < 8; ++j) acc[i][j] = 0.0f;
        for (int d0 = 0; d0 < DIM; d0 += BD) {
            __syncthreads();
            #pragma unroll
            for (int u = 0; u < 2; ++u) {
                int f = tid * 2 + u;
                int r = f >> 2;
                int dq = (f & 3) * 4;
                float4 va = *(const float4*)(lat + (size_t)(row0 + r) * DIM + d0 + dq);
                As[dq + 0][r] = va.x; As[dq + 1][r] = va.y;
                As[dq + 2][r] = va.z; As[dq + 3][r] = va.w;
                float4 vb = *(const float4*)(cb + (size_t)(kbase + kt + r) * DIM + d0 + dq);
                Bs[dq + 0][r] = vb.x; Bs[dq + 1][r] = vb.y;
                Bs[dq + 2][r] = vb.z; Bs[dq + 3][r] = vb.w;
            }
            __syncthreads();
            #pragma unroll
            for (int dd = 0; dd < BD; ++dd) {
                float4 a0 = *(const float4*)&As[dd][ty * 4];
                float4 a1 = *(const float4*)&As[dd][64 + ty * 4];
                float4 b0 = *(const float4*)&Bs[dd][tx * 4];
                float4 b1 = *(const float4*)&Bs[dd][64 + tx * 4];
                float av[8] = {a0.x, a0.y, a0.z, a0.w, a1.x, a1.y, a1.z, a1.w};
                float bv[8] = {b0.x, b0.y, b0.z, b0.w, b1.x, b1.y, b1.z, b1.w};
                #pragma unroll
                for (int i = 0; i < 8; ++i)
                    #pragma unroll
                    for (int j = 0; j < 8; ++j)
                        acc[i][j] = __builtin_fmaf(av[i], bv[j], acc[i][j]);
            }
        }
        #pragma unroll
        for (int j = 0; j < 8; ++j) {
            int cj = (j < 4) ? (tx * 4 + j) : (64 + tx * 4 + (j - 4));
            int k = kbase + kt + cj;
            #pragma unroll
            for (int i = 0; i < 8; ++i) {
                float s = __builtin_fmaf(-2.0f, acc[i][j], Sr[i]);
                if (s < bval[i]) { bval[i] = s; bidx[i] = k; }
            }
        }
    }
    #pragma unroll
    for (int i = 0; i < 8; ++i) {
        float v = bval[i];
        int ix = bidx[i];
        #pragma unroll
        for (int off = 8; off > 0; off >>= 1) {
            float ov = __shfl_xor(v, off, 16);
            int oi = __shfl_xor(ix, off, 16);
            if (ov < v || (ov == v && oi < ix)) { v = ov; ix = oi; }
        }
        if (tx == 0) {
            unsigned u = __float_as_uint(v);
            unsigned key = (u & 0x80000000u) ? ~u : (u | 0x80000000u);
            u64 pk = ((u64)key << 32) | (unsigned)ix;
            atomicMin(&best[rowid[i]], pk);
        }
    }
}

__global__ void finalize_kernel(const float* __restrict__ lat,
                                const float* __restrict__ cb,
                                const u64* __restrict__ best,
                                float* __restrict__ out_q,
                                float* __restrict__ out_idx,
                                float* __restrict__ loss_accum) {
    int n = blockIdx.x;
    int t = threadIdx.x;
    int idx = (int)(best[n] & 0xFFFFFFFFULL);
    const float2 q = ((const float2*)(cb + (size_t)idx * DIM))[t];
    const float2 l = ((const float2*)(lat + (size_t)n * DIM))[t];
    ((float2*)(out_q + (size_t)n * DIM))[t] = q;
    float dx = l.x - q.x, dy = l.y - q.y;
    float local = dx * dx + dy * dy;
    #pragma unroll
    for (int off = 32; off > 0; off >>= 1) local += __shfl_down(local, off);
    __shared__ float wsum[4];
    if ((t & 63) == 0) wsum[t >> 6] = local;
    __syncthreads();
    if (t == 0) {
        atomicAdd(loss_accum, wsum[0] + wsum[1] + wsum[2] + wsum[3]);
        out_idx[n] = (float)idx;
    }
}

__global__ void write_loss_kernel(const float* __restrict__ loss_accum,
                                  float* __restrict__ out_loss) {
    *out_loss = (1.0f + BETA) * (*loss_accum) * (1.0f / (float)((size_t)NROWS * DIM));
}

// ---------------- launch ----------------

extern "C" void kernel_launch(void* const* d_in, const int* in_sizes, int n_in,
                              void* d_out, int out_size, void* d_ws, size_t ws_size,
                              hipStream_t stream) {
    const float* lat = (const float*)d_in[0];   // [8,1024,512] f32
    const float* cb  = (const float*)d_in[1];   // [8192,512] f32

    float* out = (float*)d_out;
    float* out_q    = out;
    float* out_loss = out + (size_t)NROWS * DIM;
    float* out_idx  = out_loss + 1;

    char* ws = (char*)d_ws;

    // fast-path layout
    const size_t MATB = (size_t)NROWS * DIM * 2;            // 8 MiB per bf16 matrix
    unsigned short* Ahi = (unsigned short*)(ws);
    unsigned short* Bhi = (unsigned short*)(ws + MATB);
    float4* top2        = (float4*)(ws + 2 * MATB);         // 16 MiB
    char* tail          = ws + 2 * MATB + (size_t)NROWS * 128 * 16;
    float* SrowF        = (float*)tail;                     // 32 KiB
    int*   idxfinal     = (int*)(tail + 32768);             // 32 KiB
    float* lossF        = (float*)(tail + 65536);           // 4 B
    const size_t REQ    = (size_t)(tail - ws) + 65536 + 64;

    if (ws_size >= REQ) {
        hipLaunchKernelGGL(convert_kernel, dim3(2 * NROWS * DIM / 4 / 256), dim3(256), 0, stream,
                           lat, cb, Ahi, Bhi, lossF);
        hipLaunchKernelGGL(rownorm_kernel, dim3(NROWS / 4), dim3(256), 0, stream, lat, SrowF);
        hipLaunchKernelGGL(mfma_dist_kernel, dim3((NROWS / 128) * (KCODES / 128)), dim3(256),
                           0, stream, Ahi, Bhi, top2);
        hipLaunchKernelGGL(select_rescore_kernel, dim3(NROWS), dim3(256), 0, stream,
                           lat, cb, SrowF, top2, idxfinal);
        hipLaunchKernelGGL(finalize_idx_kernel, dim3(NROWS), dim3(256), 0, stream,
                           lat, cb, idxfinal, out_q, out_idx, lossF);
        hipLaunchKernelGGL(write_loss_kernel, dim3(1), dim3(1), 0, stream, lossF, out_loss);
    } else {
        // round-3 verified fallback
        u64*   best       = (u64*)(ws + 0);
        float* Srow       = (float*)(ws + 65536);
        float* loss_accum = (float*)(ws + 98304);
        hipLaunchKernelGGL(init_ws_kernel, dim3(32), dim3(256), 0, stream, best, loss_accum);
        hipLaunchKernelGGL(rownorm_kernel, dim3(NROWS / 4), dim3(256), 0, stream, lat, Srow);
        hipLaunchKernelGGL(dist_argmin_kernel, dim3(NROWS / BM, KCODES / KCHUNK), dim3(256),
                           0, stream, lat, cb, Srow, best);
        hipLaunchKernelGGL(finalize_kernel, dim3(NROWS), dim3(256), 0, stream,
                           lat, cb, best, out_q, out_idx, loss_accum);
        hipLaunchKernelGGL(write_loss_kernel, dim3(1), dim3(1), 0, stream, loss_accum, out_loss);
    }
}